// Round 6
// baseline (24.589 us; speedup 1.0000x reference)
//
#include <hip/hip_runtime.h>
#include <math.h>

// Gaussian splat forward: N gaussians -> res x res image (res=256, N=1024).
// SINGLE fused kernel:
//   block = one 16x16 pixel tile x one 512-gaussian half (grid 256 x 2).
//   Phase 1 (fused prep): the block's 256 threads redundantly compute the
//     expanded quadratic coefficients for the block's 512 gaussians
//     (quat->R, cov3d, project, invert; q = A X^2 + B Y^2 + C XY + c3 X +
//     c4 Y + c5, log2 domain, opacity folded in; tile-mask folded as
//     c5 -> -inf) straight into LDS. No prep kernel, no global W buffer.
//   Phase 2: the 4 waves split the 512 gaussians (128 each) and ALL cover
//     the same 256 pixels (4 px = 2x2 quad per lane), so every LDS read is
//     a wave-uniform broadcast (conflict-free). ~16 full-rate VALU + 4 exp2
//     per 24B of LDS data -> VALU/trans-bound.
//   Phase 3: LDS reduce across the 4 waves, then ONE atomicAdd per pixel
//     per block (2 per pixel total, vs 16 in the previous version).
// d_out is zeroed by a memset node; d_ws is unused.

#define TILE 16
#define GPB 512           // gaussians per block
#define GPW (GPB / 4)     // gaussians per wave

__global__ __launch_bounds__(256, 2) void gs_fused(
    const float* __restrict__ xyz, const float* __restrict__ scaling,
    const float* __restrict__ rotation, const float* __restrict__ opacity,
    const float* __restrict__ rot, float* __restrict__ out,
    int N, int res, int nt)
{
    __shared__ float4 sP[GPB];      // A, B, C, c3
    __shared__ float2 sQ[GPB];      // c4, c5eff (-inf if masked/pad)
    __shared__ float4 sR[4][64];    // per-wave partial quads

    const int tid = threadIdx.x;
    const int tX = blockIdx.x % nt, tY = blockIdx.x / nt;
    const float resf = (float)res;

    // ---------- fused per-block prep ----------
    const float tx0 = (float)(tX * TILE), tx1 = tx0 + (float)(TILE - 1);
    const float ty0 = (float)(tY * TILE), ty1 = ty0 + (float)(TILE - 1);
    #pragma unroll
    for (int k = 0; k < GPB / 256; ++k) {
        int slot = tid + k * 256;
        int n = blockIdx.y * GPB + slot;
        float4 P = make_float4(0.f, 0.f, 0.f, 0.f);
        float2 Q = make_float2(0.f, -INFINITY);
        if (n < N) {
            float qr = rotation[4*n+0], qx = rotation[4*n+1];
            float qy = rotation[4*n+2], qz = rotation[4*n+3];
            float inv = 1.0f / sqrtf(qr*qr + qx*qx + qy*qy + qz*qz);
            float r = qr*inv, x = qx*inv, y = qy*inv, z = qz*inv;

            float R00 = 1.f - 2.f*(y*y + z*z), R01 = 2.f*(x*y - r*z), R02 = 2.f*(x*z + r*y);
            float R10 = 2.f*(x*y + r*z), R11 = 1.f - 2.f*(x*x + z*z), R12 = 2.f*(y*z - r*x);
            float R20 = 2.f*(x*z - r*y), R21 = 2.f*(y*z + r*x), R22 = 1.f - 2.f*(x*x + y*y);

            float s0 = scaling[3*n+0], s1 = scaling[3*n+1], s2 = scaling[3*n+2];
            float L00 = R00*s0, L01 = R01*s1, L02 = R02*s2;
            float L10 = R10*s0, L11 = R11*s1, L12 = R12*s2;
            float L20 = R20*s0, L21 = R21*s1, L22 = R22*s2;

            float a00 = resf*rot[0], a01 = resf*rot[1], a02 = resf*rot[2];
            float a10 = resf*rot[3], a11 = resf*rot[4], a12 = resf*rot[5];
            float b00 = a00*L00 + a01*L10 + a02*L20;
            float b01 = a00*L01 + a01*L11 + a02*L21;
            float b02 = a00*L02 + a01*L12 + a02*L22;
            float b10 = a10*L00 + a11*L10 + a12*L20;
            float b11 = a10*L01 + a11*L11 + a12*L21;
            float b12 = a10*L02 + a11*L12 + a12*L22;
            float c00 = b00*b00 + b01*b01 + b02*b02;
            float c01 = b00*b10 + b01*b11 + b02*b12;   // == c10
            float c11 = b10*b10 + b11*b11 + b12*b12;

            float det = c00*c11 - c01*c01;
            float mid = 0.5f*(c00 + c11);
            float sq  = sqrtf(fmaxf(mid*mid - det, 0.1f));
            float lam = fmaxf(mid + sq, mid - sq);
            float radii = ceilf(3.0f * sqrtf(lam));

            float mx = xyz[3*n+0] * (resf*0.5f);
            float my = xyz[3*n+1] * (resf*0.5f);
            float rminx = fminf(fmaxf(mx - radii, 0.f), resf - 1.f);
            float rmaxx = fminf(fmaxf(mx + radii, 0.f), resf - 1.f);
            float rminy = fminf(fmaxf(my - radii, 0.f), resf - 1.f);
            float rmaxy = fminf(fmaxf(my + radii, 0.f), resf - 1.f);

            // this block's tile test (same float compares as reference)
            bool pass = (fminf(rmaxx, tx1) > fmaxf(rminx, tx0)) &&
                        (fminf(rmaxy, ty1) > fmaxf(rminy, ty0));

            float idet = 1.0f / det;
            const float L2E = 1.44269504088896340736f;
            float A  = -0.5f * L2E * c11 * idet;
            float B  = -0.5f * L2E * c00 * idet;
            float Cc =         L2E * c01 * idet;

            float c3 = -2.f*A*mx - Cc*my;
            float c4 = -2.f*B*my - Cc*mx;
            float c5 = A*mx*mx + B*my*my + Cc*mx*my + log2f(opacity[n]);

            P = make_float4(A, B, Cc, c3);
            Q = make_float2(c4, pass ? c5 : -INFINITY);
        }
        sP[slot] = P;
        sQ[slot] = Q;
    }
    __syncthreads();

    // ---------- main accumulation: wave w handles gaussians [w*GPW, ...) ----------
    const int w = tid >> 6, l = tid & 63;
    int px0 = tX * TILE + (l & 7) * 2;
    int py0 = tY * TILE + (l >> 3) * 2;
    float ctr = resf * 0.5f - 0.5f;
    float Xa = (float)px0 - ctr, Xb = Xa + 1.f;
    float Ya = (float)py0 - ctr, Yb = Ya + 1.f;
    float Xa2 = Xa*Xa, Xb2 = Xb*Xb, Ya2 = Ya*Ya, Yb2 = Yb*Yb;
    float XaYa = Xa*Ya, XbYa = Xb*Ya, XaYb = Xa*Yb, XbYb = Xb*Yb;

    float acc00 = 0.f, acc10 = 0.f, acc01 = 0.f, acc11 = 0.f;
    const int g0 = w * GPW;
    #pragma unroll 4
    for (int i = g0; i < g0 + GPW; ++i) {
        float4 p  = sP[i];                 // broadcast b128
        float2 qv = sQ[i];                 // broadcast b64
        float ux_a = fmaf(p.x, Xa2, p.w * Xa);
        float ux_b = fmaf(p.x, Xb2, p.w * Xb);
        float vy_a = fmaf(p.y, Ya2, fmaf(qv.x, Ya, qv.y));
        float vy_b = fmaf(p.y, Yb2, fmaf(qv.x, Yb, qv.y));
        acc00 += __builtin_amdgcn_exp2f(fmaf(p.z, XaYa, ux_a + vy_a));
        acc10 += __builtin_amdgcn_exp2f(fmaf(p.z, XbYa, ux_b + vy_a));
        acc01 += __builtin_amdgcn_exp2f(fmaf(p.z, XaYb, ux_a + vy_b));
        acc11 += __builtin_amdgcn_exp2f(fmaf(p.z, XbYb, ux_b + vy_b));
    }

    // ---------- cross-wave reduce in LDS, one atomic per pixel ----------
    sR[w][l] = make_float4(acc00, acc10, acc01, acc11);
    __syncthreads();
    if (w == 0) {
        float4 a = sR[0][l], b = sR[1][l], c = sR[2][l], d = sR[3][l];
        float s00 = (a.x + b.x) + (c.x + d.x);
        float s10 = (a.y + b.y) + (c.y + d.y);
        float s01 = (a.z + b.z) + (c.z + d.z);
        float s11 = (a.w + b.w) + (c.w + d.w);
        float* o = out + py0 * res + px0;
        atomicAdd(o,           s00);
        atomicAdd(o + 1,       s10);
        atomicAdd(o + res,     s01);
        atomicAdd(o + res + 1, s11);
    }
}

extern "C" void kernel_launch(void* const* d_in, const int* in_sizes, int n_in,
                              void* d_out, int out_size, void* d_ws, size_t ws_size,
                              hipStream_t stream) {
    const float* xyz      = (const float*)d_in[0];
    const float* scaling  = (const float*)d_in[1];
    const float* rotation = (const float*)d_in[2];
    const float* opacity  = (const float*)d_in[3];
    const float* rot      = (const float*)d_in[4];
    int N   = in_sizes[0] / 3;
    int res = (int)(sqrt((double)out_size) + 0.5);
    int nt  = res / TILE;
    int halves = (N + GPB - 1) / GPB;

    float* out = (float*)d_out;
    hipMemsetAsync(d_out, 0, (size_t)out_size * sizeof(float), stream);

    gs_fused<<<dim3(nt * nt, halves), 256, 0, stream>>>(
        xyz, scaling, rotation, opacity, rot, out, N, res, nt);
}

// Round 7
// 20.511 us; speedup vs baseline: 1.1989x; 1.1989x over previous
//
#include <hip/hip_runtime.h>
#include <math.h>

// Gaussian splat forward: N gaussians -> res x res image (res=256, N=1024).
// ONE kernel, ZERO atomics, ZERO memsets:
//   grid = nt*nt blocks (one per 16x16 tile) x 512 threads (8 waves).
//   Phase 1: block preps ALL gaussians (2/thread) into LDS: expanded
//     quadratic q = A X^2 + B Y^2 + C XY + c3 X + c4 Y + c5 (log2 domain,
//     opacity folded in; this tile's mask folds c5 -> -inf; pads too).
//   Phase 2: wave w accumulates gaussians [w*128, (w+1)*128) over the FULL
//     256-px tile (2x2 quad per lane) -- every LDS read is a wave-uniform
//     broadcast (conflict-free). ~20 full-rate VALU + 4 exp2 per gaussian
//     per lane (4 pixel-pairs).
//   Phase 3: 8-wave LDS reduce; wave 0 writes each pixel exactly once with
//     plain coalesced float2 stores. Full overwrite -> no init required.

#define TILE 16
#define MAXG 1024        // gaussians staged per chunk (N==1024 -> one chunk)
#define NW   8           // waves per block
#define GPW  (MAXG / NW) // gaussians per wave per chunk

__global__ __launch_bounds__(512, 1) void gs_fused(
    const float* __restrict__ xyz, const float* __restrict__ scaling,
    const float* __restrict__ rotation, const float* __restrict__ opacity,
    const float* __restrict__ rot, float* __restrict__ out,
    int N, int res, int nt)
{
    __shared__ float4 sP[MAXG];      // A, B, C, c3
    __shared__ float2 sQ[MAXG];      // c4, c5eff (-inf if masked/pad)
    __shared__ float4 sR[NW][64];    // per-wave partial 2x2 quads

    const int tid = threadIdx.x;
    const int w = tid >> 6, l = tid & 63;
    const int tX = blockIdx.x % nt, tY = blockIdx.x / nt;
    const float resf = (float)res;

    // this lane's 2x2 pixel quad (wave covers the whole 16x16 tile)
    const int px0 = tX * TILE + (l & 7) * 2;
    const int py0 = tY * TILE + (l >> 3) * 2;
    const float ctr = resf * 0.5f - 0.5f;
    const float Xa = (float)px0 - ctr, Xb = Xa + 1.f;
    const float Ya = (float)py0 - ctr, Yb = Ya + 1.f;
    const float Xa2 = Xa*Xa, Xb2 = Xb*Xb, Ya2 = Ya*Ya, Yb2 = Yb*Yb;
    const float XaYa = Xa*Ya, XbYa = Xb*Ya, XaYb = Xa*Yb, XbYb = Xb*Yb;

    const float tx0 = (float)(tX * TILE), tx1 = tx0 + (float)(TILE - 1);
    const float ty0 = (float)(tY * TILE), ty1 = ty0 + (float)(TILE - 1);

    float acc00 = 0.f, acc10 = 0.f, acc01 = 0.f, acc11 = 0.f;

    for (int base = 0; base < N; base += MAXG) {
        const int C = min(MAXG, N - base);

        // ---------- stage this chunk's coefficients into LDS ----------
        #pragma unroll
        for (int k = 0; k < MAXG / 512; ++k) {
            int slot = tid + k * 512;
            float4 P = make_float4(0.f, 0.f, 0.f, 0.f);
            float2 Q = make_float2(0.f, -INFINITY);
            if (slot < C) {
                int n = base + slot;
                float qr = rotation[4*n+0], qx = rotation[4*n+1];
                float qy = rotation[4*n+2], qz = rotation[4*n+3];
                float inv = 1.0f / sqrtf(qr*qr + qx*qx + qy*qy + qz*qz);
                float r = qr*inv, x = qx*inv, y = qy*inv, z = qz*inv;

                float R00 = 1.f - 2.f*(y*y + z*z), R01 = 2.f*(x*y - r*z), R02 = 2.f*(x*z + r*y);
                float R10 = 2.f*(x*y + r*z), R11 = 1.f - 2.f*(x*x + z*z), R12 = 2.f*(y*z - r*x);
                float R20 = 2.f*(x*z - r*y), R21 = 2.f*(y*z + r*x), R22 = 1.f - 2.f*(x*x + y*y);

                float s0 = scaling[3*n+0], s1 = scaling[3*n+1], s2 = scaling[3*n+2];
                float L00 = R00*s0, L01 = R01*s1, L02 = R02*s2;
                float L10 = R10*s0, L11 = R11*s1, L12 = R12*s2;
                float L20 = R20*s0, L21 = R21*s1, L22 = R22*s2;

                float a00 = resf*rot[0], a01 = resf*rot[1], a02 = resf*rot[2];
                float a10 = resf*rot[3], a11 = resf*rot[4], a12 = resf*rot[5];
                float b00 = a00*L00 + a01*L10 + a02*L20;
                float b01 = a00*L01 + a01*L11 + a02*L21;
                float b02 = a00*L02 + a01*L12 + a02*L22;
                float b10 = a10*L00 + a11*L10 + a12*L20;
                float b11 = a10*L01 + a11*L11 + a12*L21;
                float b12 = a10*L02 + a11*L12 + a12*L22;
                float c00 = b00*b00 + b01*b01 + b02*b02;
                float c01 = b00*b10 + b01*b11 + b02*b12;   // == c10
                float c11 = b10*b10 + b11*b11 + b12*b12;

                float det = c00*c11 - c01*c01;
                float mid = 0.5f*(c00 + c11);
                float sq  = sqrtf(fmaxf(mid*mid - det, 0.1f));
                float lam = fmaxf(mid + sq, mid - sq);
                float radii = ceilf(3.0f * sqrtf(lam));

                float mx = xyz[3*n+0] * (resf*0.5f);
                float my = xyz[3*n+1] * (resf*0.5f);
                float rminx = fminf(fmaxf(mx - radii, 0.f), resf - 1.f);
                float rmaxx = fminf(fmaxf(mx + radii, 0.f), resf - 1.f);
                float rminy = fminf(fmaxf(my - radii, 0.f), resf - 1.f);
                float rmaxy = fminf(fmaxf(my + radii, 0.f), resf - 1.f);

                bool pass = (fminf(rmaxx, tx1) > fmaxf(rminx, tx0)) &&
                            (fminf(rmaxy, ty1) > fmaxf(rminy, ty0));

                float idet = 1.0f / det;
                const float L2E = 1.44269504088896340736f;
                float A  = -0.5f * L2E * c11 * idet;
                float B  = -0.5f * L2E * c00 * idet;
                float Cc =         L2E * c01 * idet;

                float c3 = -2.f*A*mx - Cc*my;
                float c4 = -2.f*B*my - Cc*mx;
                float c5 = A*mx*mx + B*my*my + Cc*mx*my + log2f(opacity[n]);

                P = make_float4(A, B, Cc, c3);
                Q = make_float2(c4, pass ? c5 : -INFINITY);
            }
            sP[slot] = P;
            sQ[slot] = Q;
        }
        __syncthreads();

        // ---------- accumulate: wave w takes gaussians [w*GPW, (w+1)*GPW) ----------
        const int g0 = w * GPW;
        #pragma unroll 4
        for (int i = g0; i < g0 + GPW; ++i) {
            float4 p  = sP[i];                 // broadcast b128
            float2 qv = sQ[i];                 // broadcast b64
            float ux_a = fmaf(p.x, Xa2, p.w * Xa);
            float ux_b = fmaf(p.x, Xb2, p.w * Xb);
            float vy_a = fmaf(p.y, Ya2, fmaf(qv.x, Ya, qv.y));
            float vy_b = fmaf(p.y, Yb2, fmaf(qv.x, Yb, qv.y));
            acc00 += __builtin_amdgcn_exp2f(fmaf(p.z, XaYa, ux_a + vy_a));
            acc10 += __builtin_amdgcn_exp2f(fmaf(p.z, XbYa, ux_b + vy_a));
            acc01 += __builtin_amdgcn_exp2f(fmaf(p.z, XaYb, ux_a + vy_b));
            acc11 += __builtin_amdgcn_exp2f(fmaf(p.z, XbYb, ux_b + vy_b));
        }
        __syncthreads();   // safe to restage LDS next chunk
    }

    // ---------- 8-wave reduce in LDS, plain stores (each pixel written once) ----------
    sR[w][l] = make_float4(acc00, acc10, acc01, acc11);
    __syncthreads();
    if (w == 0) {
        float4 s = sR[0][l];
        #pragma unroll
        for (int k = 1; k < NW; ++k) {
            float4 t = sR[k][l];
            s.x += t.x; s.y += t.y; s.z += t.z; s.w += t.w;
        }
        float* o = out + py0 * res + px0;
        *(float2*)(o)       = make_float2(s.x, s.y);
        *(float2*)(o + res) = make_float2(s.z, s.w);
    }
}

extern "C" void kernel_launch(void* const* d_in, const int* in_sizes, int n_in,
                              void* d_out, int out_size, void* d_ws, size_t ws_size,
                              hipStream_t stream) {
    const float* xyz      = (const float*)d_in[0];
    const float* scaling  = (const float*)d_in[1];
    const float* rotation = (const float*)d_in[2];
    const float* opacity  = (const float*)d_in[3];
    const float* rot      = (const float*)d_in[4];
    int N   = in_sizes[0] / 3;
    int res = (int)(sqrt((double)out_size) + 0.5);
    int nt  = res / TILE;

    float* out = (float*)d_out;

    gs_fused<<<dim3(nt * nt), 512, 0, stream>>>(
        xyz, scaling, rotation, opacity, rot, out, N, res, nt);
}

// Round 8
// 19.603 us; speedup vs baseline: 1.2544x; 1.0463x over previous
//
#include <hip/hip_runtime.h>
#include <math.h>

// Gaussian splat forward: N gaussians -> res x res image (res=256, N=1024).
// ONE kernel, ZERO atomics, ZERO memsets:
//   grid = nt*nt = 256 blocks (one per 16x16 tile) x 1024 threads (16 waves,
//   4 waves/SIMD for latency hiding).
//   Phase 1: block preps ALL gaussians (1/thread) into LDS: expanded
//     quadratic q = A X^2 + B Y^2 + C XY + c3 X + c4 Y + c5 (log2 domain,
//     opacity folded in; this tile's mask folds c5 -> -inf; pads too).
//   Phase 2: wave w accumulates gaussians [w*64, (w+1)*64) over the FULL
//     256-px tile (2x2 quad per lane). LDS reads are wave-uniform broadcasts
//     (conflict-free). Delta-form quad eval: qaa direct (5 fma), then
//     qba=qaa+dX, qab=qaa+dY, qbb=qab+dX+C  -> 17 VALU + 4 exp2 per gaussian.
//     Masked c5=-inf propagates additively to all 4 pixels (exp2->0, no inf*0).
//   Phase 3: 16-wave LDS reduce; wave 0 writes each pixel exactly once with
//     plain coalesced float2 stores. Full overwrite -> no init required.

#define TILE 16
#define MAXG 1024        // gaussians staged per chunk (N==1024 -> one chunk)
#define NW   16          // waves per block
#define GPW  (MAXG / NW) // gaussians per wave per chunk

__global__ __launch_bounds__(1024, 1) void gs_fused(
    const float* __restrict__ xyz, const float* __restrict__ scaling,
    const float* __restrict__ rotation, const float* __restrict__ opacity,
    const float* __restrict__ rot, float* __restrict__ out,
    int N, int res, int nt)
{
    __shared__ float4 sP[MAXG];      // A, B, C, c3
    __shared__ float2 sQ[MAXG];      // c4, c5eff (-inf if masked/pad)
    __shared__ float4 sR[NW][64];    // per-wave partial 2x2 quads

    const int tid = threadIdx.x;
    const int w = tid >> 6, l = tid & 63;
    const int tX = blockIdx.x % nt, tY = blockIdx.x / nt;
    const float resf = (float)res;

    // this lane's 2x2 pixel quad (each wave covers the whole 16x16 tile)
    const int px0 = tX * TILE + (l & 7) * 2;
    const int py0 = tY * TILE + (l >> 3) * 2;
    const float ctr = resf * 0.5f - 0.5f;
    const float Xa = (float)px0 - ctr, Xb = Xa + 1.f;
    const float Ya = (float)py0 - ctr, Yb = Ya + 1.f;
    const float XaYa = Xa * Ya;
    const float sXab = Xa + Xb;      // 2*Xa + 1
    const float sYab = Ya + Yb;      // 2*Ya + 1

    const float tx0 = (float)(tX * TILE), tx1 = tx0 + (float)(TILE - 1);
    const float ty0 = (float)(tY * TILE), ty1 = ty0 + (float)(TILE - 1);

    float acc00 = 0.f, acc10 = 0.f, acc01 = 0.f, acc11 = 0.f;

    for (int base = 0; base < N; base += MAXG) {
        const int C = min(MAXG, N - base);

        // ---------- stage this chunk's coefficients into LDS ----------
        for (int slot = tid; slot < MAXG; slot += 1024) {
            float4 P = make_float4(0.f, 0.f, 0.f, 0.f);
            float2 Q = make_float2(0.f, -INFINITY);
            if (slot < C) {
                int n = base + slot;
                float qr = rotation[4*n+0], qx = rotation[4*n+1];
                float qy = rotation[4*n+2], qz = rotation[4*n+3];
                float inv = 1.0f / sqrtf(qr*qr + qx*qx + qy*qy + qz*qz);
                float r = qr*inv, x = qx*inv, y = qy*inv, z = qz*inv;

                float R00 = 1.f - 2.f*(y*y + z*z), R01 = 2.f*(x*y - r*z), R02 = 2.f*(x*z + r*y);
                float R10 = 2.f*(x*y + r*z), R11 = 1.f - 2.f*(x*x + z*z), R12 = 2.f*(y*z - r*x);
                float R20 = 2.f*(x*z - r*y), R21 = 2.f*(y*z + r*x), R22 = 1.f - 2.f*(x*x + y*y);

                float s0 = scaling[3*n+0], s1 = scaling[3*n+1], s2 = scaling[3*n+2];
                float L00 = R00*s0, L01 = R01*s1, L02 = R02*s2;
                float L10 = R10*s0, L11 = R11*s1, L12 = R12*s2;
                float L20 = R20*s0, L21 = R21*s1, L22 = R22*s2;

                float a00 = resf*rot[0], a01 = resf*rot[1], a02 = resf*rot[2];
                float a10 = resf*rot[3], a11 = resf*rot[4], a12 = resf*rot[5];
                float b00 = a00*L00 + a01*L10 + a02*L20;
                float b01 = a00*L01 + a01*L11 + a02*L21;
                float b02 = a00*L02 + a01*L12 + a02*L22;
                float b10 = a10*L00 + a11*L10 + a12*L20;
                float b11 = a10*L01 + a11*L11 + a12*L21;
                float b12 = a10*L02 + a11*L12 + a12*L22;
                float c00 = b00*b00 + b01*b01 + b02*b02;
                float c01 = b00*b10 + b01*b11 + b02*b12;   // == c10
                float c11 = b10*b10 + b11*b11 + b12*b12;

                float det = c00*c11 - c01*c01;
                float mid = 0.5f*(c00 + c11);
                float sq  = sqrtf(fmaxf(mid*mid - det, 0.1f));
                float lam = fmaxf(mid + sq, mid - sq);
                float radii = ceilf(3.0f * sqrtf(lam));

                float mx = xyz[3*n+0] * (resf*0.5f);
                float my = xyz[3*n+1] * (resf*0.5f);
                float rminx = fminf(fmaxf(mx - radii, 0.f), resf - 1.f);
                float rmaxx = fminf(fmaxf(mx + radii, 0.f), resf - 1.f);
                float rminy = fminf(fmaxf(my - radii, 0.f), resf - 1.f);
                float rmaxy = fminf(fmaxf(my + radii, 0.f), resf - 1.f);

                bool pass = (fminf(rmaxx, tx1) > fmaxf(rminx, tx0)) &&
                            (fminf(rmaxy, ty1) > fmaxf(rminy, ty0));

                float idet = 1.0f / det;
                const float L2E = 1.44269504088896340736f;
                float A  = -0.5f * L2E * c11 * idet;
                float B  = -0.5f * L2E * c00 * idet;
                float Cc =         L2E * c01 * idet;

                float c3 = -2.f*A*mx - Cc*my;
                float c4 = -2.f*B*my - Cc*mx;
                float c5 = A*mx*mx + B*my*my + Cc*mx*my + log2f(opacity[n]);

                P = make_float4(A, B, Cc, c3);
                Q = make_float2(c4, pass ? c5 : -INFINITY);
            }
            sP[slot] = P;
            sQ[slot] = Q;
        }
        __syncthreads();

        // ---------- accumulate: wave w takes gaussians [w*GPW, (w+1)*GPW) ----------
        const int g0 = w * GPW;
        #pragma unroll 4
        for (int i = g0; i < g0 + GPW; ++i) {
            float4 p  = sP[i];                 // broadcast b128
            float2 qv = sQ[i];                 // broadcast b64
            // direct eval at (Xa,Ya):
            float t1  = fmaf(p.x, Xa, p.w);    // A*Xa + c3
            float t3  = fmaf(p.y, Ya, qv.x);   // B*Ya + c4
            float t2  = fmaf(t1, Xa, qv.y);    // + c5eff (=-inf if masked)
            float t4  = fmaf(t3, Ya, t2);
            float qaa = fmaf(p.z, XaYa, t4);
            // deltas: dX = q(X+1,Y)-q(X,Y) = A(2X+1)+c3' ... evaluated at col a
            float dx0 = fmaf(p.x, sXab, p.w);  // A(2Xa+1) + c3
            float dy0 = fmaf(p.y, sYab, qv.x); // B(2Ya+1) + c4
            float dX  = fmaf(p.z, Ya, dx0);    // + C*Ya
            float dY  = fmaf(p.z, Xa, dy0);    // + C*Xa
            float qba = qaa + dX;
            float qab = qaa + dY;
            float qbb = qab + (dX + p.z);      // + C (cross term step)
            acc00 += __builtin_amdgcn_exp2f(qaa);
            acc10 += __builtin_amdgcn_exp2f(qba);
            acc01 += __builtin_amdgcn_exp2f(qab);
            acc11 += __builtin_amdgcn_exp2f(qbb);
        }
        __syncthreads();   // safe to restage LDS next chunk
    }

    // ---------- 16-wave reduce in LDS, plain stores (each pixel written once) ----------
    sR[w][l] = make_float4(acc00, acc10, acc01, acc11);
    __syncthreads();
    if (w == 0) {
        float4 s = sR[0][l];
        #pragma unroll
        for (int k = 1; k < NW; ++k) {
            float4 t = sR[k][l];
            s.x += t.x; s.y += t.y; s.z += t.z; s.w += t.w;
        }
        float* o = out + py0 * res + px0;
        *(float2*)(o)       = make_float2(s.x, s.y);
        *(float2*)(o + res) = make_float2(s.z, s.w);
    }
}

extern "C" void kernel_launch(void* const* d_in, const int* in_sizes, int n_in,
                              void* d_out, int out_size, void* d_ws, size_t ws_size,
                              hipStream_t stream) {
    const float* xyz      = (const float*)d_in[0];
    const float* scaling  = (const float*)d_in[1];
    const float* rotation = (const float*)d_in[2];
    const float* opacity  = (const float*)d_in[3];
    const float* rot      = (const float*)d_in[4];
    int N   = in_sizes[0] / 3;
    int res = (int)(sqrt((double)out_size) + 0.5);
    int nt  = res / TILE;

    float* out = (float*)d_out;

    gs_fused<<<dim3(nt * nt), 1024, 0, stream>>>(
        xyz, scaling, rotation, opacity, rot, out, N, res, nt);
}